// Round 4
// baseline (1745.045 us; speedup 1.0000x reference)
//
// CurvGN 2-layer GNN, MI355X gfx950. Round 4: split the k_edge monolith.
// R3 post-mortem: k_edge 644us, MfmaUtil 9%, VALU 23%, HBM 14%, occ 35% ->
// barrier-convoy across ~9 syncs with 2.9 blocks/CU. R4: three single-purpose
// kernels (mlp1a gather+GEMM1 / mlp1b GEMM2+exp+segsum, in-place u1->eow1 /
// mlp2 standalone), higher occupancy each, footprint unchanged (574 MB).
#include <hip/hip_runtime.h>
#include <hip/hip_bf16.h>
#include <math.h>

#define N_NODESC 50000
#define N_EDGESC 800000
#define F_INC 512
#define HIDC 256
#define N_CLSC 40
#define W_DIMC 50
#define HN (2*N_NODESC)
#define NB_SCAN 196   // ceil(100000/512)

typedef __bf16 bf16;
typedef __bf16 bf16x8 __attribute__((ext_vector_type(8)));
typedef __bf16 bf16x4 __attribute__((ext_vector_type(4)));
typedef __bf16 bf16x2 __attribute__((ext_vector_type(2)));
typedef float  f32x4  __attribute__((ext_vector_type(4)));
typedef float  f32x2  __attribute__((ext_vector_type(2)));

// ---------------- CSR build ----------------
__global__ void k_hist(const int* __restrict__ ei, int* __restrict__ hist) {
    int e = blockIdx.x*256 + threadIdx.x;
    if (e < N_EDGESC) {
        atomicAdd(&hist[ei[e]], 1);
        atomicAdd(&hist[N_NODESC + ei[N_EDGESC + e]], 1);
    }
}
__global__ void k_copy(int* d, const int* s, int n) {
    int i = blockIdx.x*256 + threadIdx.x;
    if (i < n) d[i] = s[i];
}
__global__ void k_scan_part(const int* __restrict__ hist, int* __restrict__ part) {
    __shared__ int lds[512];
    int t = threadIdx.x;
    int i = blockIdx.x*512 + t;
    lds[t] = (i < HN) ? hist[i] : 0;
    __syncthreads();
    for (int off = 256; off > 0; off >>= 1) {
        if (t < off) lds[t] += lds[t+off];
        __syncthreads();
    }
    if (t == 0) part[blockIdx.x] = lds[0];
}
__global__ void k_scan_mid(const int* __restrict__ part, int* __restrict__ partx) {
    __shared__ int lds[256];
    int t = threadIdx.x;
    int v = (t < NB_SCAN) ? part[t] : 0;
    lds[t] = v;
    __syncthreads();
    for (int off = 1; off < 256; off <<= 1) {
        int add = (t >= off) ? lds[t-off] : 0;
        __syncthreads();
        lds[t] += add;
        __syncthreads();
    }
    partx[t] = lds[t] - v;  // exclusive
}
__global__ void k_scan_apply(const int* __restrict__ hist, const int* __restrict__ partx,
                             int* __restrict__ basev) {
    __shared__ int lds[512];
    int t = threadIdx.x;
    int i = blockIdx.x*512 + t;
    int v = (i < HN) ? hist[i] : 0;
    lds[t] = v;
    __syncthreads();
    for (int off = 1; off < 512; off <<= 1) {
        int add = (t >= off) ? lds[t-off] : 0;
        __syncthreads();
        lds[t] += add;
        __syncthreads();
    }
    if (i < HN) basev[i] = lds[t] - v + partx[blockIdx.x];
}
// perm_src[p]=e (src-order); spd[q]=p, svd[q]=src (dst-order)
__global__ void k_scatter(const int* __restrict__ ei, int* __restrict__ cursor,
                          int* __restrict__ perm_src,
                          int* __restrict__ spd, int* __restrict__ svd) {
    int e = blockIdx.x*256 + threadIdx.x;
    if (e >= N_EDGESC) return;
    int s = ei[e];
    int d = ei[N_EDGESC + e];
    int p = atomicAdd(&cursor[s], 1);
    perm_src[p] = e;
    int q = atomicAdd(&cursor[N_NODESC + d], 1) - N_EDGESC;
    spd[q] = p;
    svd[q] = s;
}

// ------------- weight transpose/convert: dst[n*Kp+k] = src[k*Ns+n] -------------
__global__ void k_tconv(const float* __restrict__ src, bf16* __restrict__ dst,
                        int Ks, int Ns, int Kp, int Np) {
    int idx = blockIdx.x*256 + threadIdx.x;
    if (idx >= Kp*Np) return;
    int n = idx / Kp, k = idx - n*Kp;
    float v = (k < Ks && n < Ns) ? src[k*Ns + n] : 0.f;
    dst[idx] = (bf16)v;
}

// ------------- h1 = x @ W1 + b1  (bf16 MFMA, bf16 out) -------------
__global__ __launch_bounds__(256) void k_h1(const float* __restrict__ x,
                                            const bf16* __restrict__ W1t,
                                            const float* __restrict__ b1,
                                            bf16* __restrict__ h1) {
    __shared__ __align__(16) bf16 a_lds[64*40];
    int tid = threadIdx.x;
    int lane = tid & 63, wv = tid >> 6;
    int l15 = lane & 15, quad = lane >> 4;
    int r0 = blockIdx.x * 64;
    f32x4 acc[4][4] = {};
    for (int ks = 0; ks < 16; ++ks) {
        #pragma unroll
        for (int i = 0; i < 2; ++i) {
            int idx = tid + i*256;          // 512 float4 = 64 rows x 32 k
            int rl = idx >> 3, c4 = idx & 7;
            int rg = r0 + rl;
            f32x4 v = {};
            if (rg < N_NODESC) v = *(const f32x4*)&x[(size_t)rg*F_INC + ks*32 + c4*4];
            bf16x4 b; b[0]=(bf16)v[0]; b[1]=(bf16)v[1]; b[2]=(bf16)v[2]; b[3]=(bf16)v[3];
            *(bf16x4*)&a_lds[rl*40 + c4*4] = b;
        }
        __syncthreads();
        bf16x8 af[4], bfr[4];
        #pragma unroll
        for (int mt = 0; mt < 4; ++mt)
            af[mt] = *(const bf16x8*)&a_lds[(mt*16 + l15)*40 + quad*8];
        #pragma unroll
        for (int nt = 0; nt < 4; ++nt) {
            int n = wv*64 + nt*16 + l15;
            bfr[nt] = *(const bf16x8*)&W1t[n*F_INC + ks*32 + quad*8];
        }
        #pragma unroll
        for (int mt = 0; mt < 4; ++mt)
            #pragma unroll
            for (int nt = 0; nt < 4; ++nt)
                acc[mt][nt] = __builtin_amdgcn_mfma_f32_16x16x32_bf16(af[mt], bfr[nt], acc[mt][nt], 0, 0, 0);
        __syncthreads();
    }
    #pragma unroll
    for (int nt = 0; nt < 4; ++nt) {
        int col = wv*64 + nt*16 + l15;
        float bias = b1[col];
        #pragma unroll
        for (int mt = 0; mt < 4; ++mt)
            #pragma unroll
            for (int r = 0; r < 4; ++r) {
                int row = r0 + mt*16 + quad*4 + r;
                if (row < N_NODESC) h1[(size_t)row*HIDC + col] = (bf16)(acc[mt][nt][r] + bias);
            }
    }
}

// ------------- MLP1 stage 1: u1 = prelu(wm @ w0), src-order rows -------------
__global__ __launch_bounds__(256) void k_mlp1a(
    const float* __restrict__ w_mul, const int* __restrict__ perm_src,
    const bf16* __restrict__ w0t, const float* __restrict__ a1,
    bf16* __restrict__ u1) {
    __shared__ __align__(16) bf16 wm[64*72];    // A tile, K padded 50->64
    __shared__ __align__(16) bf16 bw[256*72];   // w0t staged, padded stride
    __shared__ int e_lds[64];
    int tid = threadIdx.x;
    int lane = tid & 63, wv = tid >> 6;
    int l15 = lane & 15, quad = lane >> 4;
    int p0 = blockIdx.x * 64;

    if (tid < 64) e_lds[tid] = perm_src[p0 + tid];
    // stage B (w0t 256x64) into padded LDS: 2048 x bf16x8
    #pragma unroll
    for (int i = 0; i < 8; ++i) {
        int idx = i*256 + tid;
        int n = idx >> 3, j = idx & 7;
        *(bf16x8*)&bw[n*72 + j*8] = *(const bf16x8*)&w0t[n*64 + j*8];
    }
    __syncthreads();   // e_lds ready
    // stage A: gather w_mul rows as f32x2 -> packed bf16x2 (64 rows x 25 pairs)
    #pragma unroll
    for (int i = 0; i < 7; ++i) {
        int idx = i*256 + tid;
        if (idx < 1600) {
            int row = idx / 25;
            int k = 2*(idx - row*25);
            f32x2 v = *(const f32x2*)&w_mul[(size_t)e_lds[row]*W_DIMC + k];
            bf16x2 b; b[0] = (bf16)v[0]; b[1] = (bf16)v[1];
            *(bf16x2*)&wm[row*72 + k] = b;
        }
    }
    // zero pad cols 50..63
    #pragma unroll
    for (int i = 0; i < 2; ++i) {
        int idx = i*256 + tid;
        if (idx < 448) {
            int row = idx / 7, c = 50 + 2*(idx - row*7);
            bf16x2 z; z[0] = (bf16)0.f; z[1] = (bf16)0.f;
            *(bf16x2*)&wm[row*72 + c] = z;
        }
    }
    __syncthreads();

    f32x4 acc[4][4] = {};
    #pragma unroll
    for (int ks = 0; ks < 2; ++ks) {
        bf16x8 af[4], bfr[4];
        #pragma unroll
        for (int mt = 0; mt < 4; ++mt)
            af[mt] = *(const bf16x8*)&wm[(mt*16 + l15)*72 + ks*32 + quad*8];
        #pragma unroll
        for (int i = 0; i < 4; ++i)
            bfr[i] = *(const bf16x8*)&bw[(wv*64 + i*16 + l15)*72 + ks*32 + quad*8];
        #pragma unroll
        for (int mt = 0; mt < 4; ++mt)
            #pragma unroll
            for (int i = 0; i < 4; ++i)
                acc[mt][i] = __builtin_amdgcn_mfma_f32_16x16x32_bf16(af[mt], bfr[i], acc[mt][i], 0, 0, 0);
    }
    #pragma unroll
    for (int i = 0; i < 4; ++i) {
        int col = wv*64 + i*16 + l15;
        float al = a1[col];
        #pragma unroll
        for (int mt = 0; mt < 4; ++mt)
            #pragma unroll
            for (int r = 0; r < 4; ++r) {
                float v = acc[mt][i][r];
                v = (v >= 0.f) ? v : al*v;
                u1[(size_t)(p0 + mt*16 + quad*4 + r)*HIDC + col] = (bf16)v;
            }
    }
}

// ------------- MLP1 stage 2: eow1 = exp(u1 @ w1 + b), IN PLACE over u1; + s1 segsum ----
__global__ __launch_bounds__(256) void k_mlp1b(
    const int* __restrict__ perm_src, const int* __restrict__ ei,
    const bf16* __restrict__ w1t, const float* __restrict__ bb1,
    bf16* __restrict__ eow1,      // in: u1 rows (this block's), out: exp rows
    float* __restrict__ s1) {
    __shared__ __align__(16) bf16 t1[64*264];
    __shared__ int sv[64];
    int tid = threadIdx.x;
    int lane = tid & 63, wv = tid >> 6;
    int l15 = lane & 15, quad = lane >> 4;
    int p0 = blockIdx.x * 64;

    if (tid < 64) sv[tid] = ei[perm_src[p0 + tid]];
    // stage A: contiguous u1 rows p0..p0+63 (2048 x bf16x8)
    #pragma unroll
    for (int i = 0; i < 8; ++i) {
        int idx = i*256 + tid;
        int row = idx >> 5, j = idx & 31;
        *(bf16x8*)&t1[row*264 + j*8] = *(const bf16x8*)&eow1[(size_t)(p0 + row)*HIDC + j*8];
    }
    __syncthreads();

    f32x4 acc[4][4] = {};
    #pragma unroll
    for (int ks = 0; ks < 8; ++ks) {
        bf16x8 af[4], bfr[4];
        #pragma unroll
        for (int mt = 0; mt < 4; ++mt)
            af[mt] = *(const bf16x8*)&t1[(mt*16 + l15)*264 + ks*32 + quad*8];
        #pragma unroll
        for (int i = 0; i < 4; ++i)
            bfr[i] = *(const bf16x8*)&w1t[(wv*64 + i*16 + l15)*HIDC + ks*32 + quad*8];
        #pragma unroll
        for (int mt = 0; mt < 4; ++mt)
            #pragma unroll
            for (int i = 0; i < 4; ++i)
                acc[mt][i] = __builtin_amdgcn_mfma_f32_16x16x32_bf16(af[mt], bfr[i], acc[mt][i], 0, 0, 0);
    }
    __syncthreads();   // all t1 reads done
    #pragma unroll
    for (int i = 0; i < 4; ++i) {
        int col = wv*64 + i*16 + l15;
        float bias = bb1[col];
        #pragma unroll
        for (int mt = 0; mt < 4; ++mt)
            #pragma unroll
            for (int r = 0; r < 4; ++r)
                t1[(mt*16 + quad*4 + r)*264 + col] = (bf16)__expf(acc[mt][i][r] + bias);
    }
    __syncthreads();
    // write back in place (rows owned exclusively by this block)
    #pragma unroll
    for (int i = 0; i < 8; ++i) {
        int idx = i*256 + tid;
        int row = idx >> 5, j = idx & 31;
        *(bf16x8*)&eow1[(size_t)(p0 + row)*HIDC + j*8] = *(const bf16x8*)&t1[row*264 + j*8];
    }
    // seg-sum s1 (fixed-trip, wave-uniform flush)
    {
        int c = tid;
        float acc2 = 0.f;
        #pragma unroll
        for (int r = 0; r < 64; ++r) {
            acc2 += (float)t1[r*264 + c];
            if (r == 63 || sv[r+1] != sv[r]) {
                atomicAdd(&s1[(size_t)sv[r]*HIDC + c], acc2);
                acc2 = 0.f;
            }
        }
    }
}

// ------------- MLP2 (both stages) + s2 segsum, src-order -------------
__global__ __launch_bounds__(256) void k_mlp2(
    const float* __restrict__ w_mul, const int* __restrict__ perm_src,
    const int* __restrict__ ei,
    const bf16* __restrict__ w20t, const float* __restrict__ a2,
    const bf16* __restrict__ w21t, const float* __restrict__ bb2,
    bf16* __restrict__ eow2, float* __restrict__ s2) {
    __shared__ __align__(16) bf16 wm[64*72];
    __shared__ __align__(16) bf16 t2[64*72];
    __shared__ int e_lds[64], sv[64];
    int tid = threadIdx.x;
    int lane = tid & 63, wv = tid >> 6;
    int l15 = lane & 15, quad = lane >> 4;
    int p0 = blockIdx.x * 64;

    if (tid < 64) {
        int e = perm_src[p0 + tid];
        e_lds[tid] = e;
        sv[tid] = ei[e];
    }
    __syncthreads();
    // stage wm (gathered f32x2 -> bf16x2)
    #pragma unroll
    for (int i = 0; i < 7; ++i) {
        int idx = i*256 + tid;
        if (idx < 1600) {
            int row = idx / 25;
            int k = 2*(idx - row*25);
            f32x2 v = *(const f32x2*)&w_mul[(size_t)e_lds[row]*W_DIMC + k];
            bf16x2 b; b[0] = (bf16)v[0]; b[1] = (bf16)v[1];
            *(bf16x2*)&wm[row*72 + k] = b;
        }
    }
    #pragma unroll
    for (int i = 0; i < 2; ++i) {   // wm pad cols 50..63
        int idx = i*256 + tid;
        if (idx < 448) {
            int row = idx / 7, c = 50 + 2*(idx - row*7);
            bf16x2 z; z[0] = (bf16)0.f; z[1] = (bf16)0.f;
            *(bf16x2*)&wm[row*72 + c] = z;
        }
    }
    #pragma unroll
    for (int i = 0; i < 2; ++i) {   // t2 pad cols 48..63
        int idx = i*256 + tid;
        // 64 rows x 8 bf16x2 = 512
        int row = idx >> 3, c = 48 + 2*(idx & 7);
        bf16x2 z; z[0] = (bf16)0.f; z[1] = (bf16)0.f;
        *(bf16x2*)&t2[row*72 + c] = z;
    }
    __syncthreads();

    // stage 1: wave wv owns rows wv*16..+15; cols 0..47
    {
        f32x4 acc[3] = {};
        #pragma unroll
        for (int ks = 0; ks < 2; ++ks) {
            bf16x8 af = *(const bf16x8*)&wm[(wv*16 + l15)*72 + ks*32 + quad*8];
            #pragma unroll
            for (int i = 0; i < 3; ++i) {
                bf16x8 bfr = *(const bf16x8*)&w20t[(i*16 + l15)*64 + ks*32 + quad*8];
                acc[i] = __builtin_amdgcn_mfma_f32_16x16x32_bf16(af, bfr, acc[i], 0, 0, 0);
            }
        }
        #pragma unroll
        for (int i = 0; i < 3; ++i) {
            int col = i*16 + l15;
            float al = (col < N_CLSC) ? a2[col] : 0.f;
            #pragma unroll
            for (int r = 0; r < 4; ++r) {
                float v = acc[i][r];
                v = (v >= 0.f) ? v : al*v;
                t2[(wv*16 + quad*4 + r)*72 + col] = (bf16)v;
            }
        }
    }
    __syncthreads();
    // stage 2: t2 @ w21t -> exp -> overwrite t2 cols<40
    {
        f32x4 acc[3] = {};
        #pragma unroll
        for (int ks = 0; ks < 2; ++ks) {
            bf16x8 af = *(const bf16x8*)&t2[(wv*16 + l15)*72 + ks*32 + quad*8];
            #pragma unroll
            for (int i = 0; i < 3; ++i) {
                bf16x8 bfr = *(const bf16x8*)&w21t[(i*16 + l15)*64 + ks*32 + quad*8];
                acc[i] = __builtin_amdgcn_mfma_f32_16x16x32_bf16(af, bfr, acc[i], 0, 0, 0);
            }
        }
        __syncthreads();
        #pragma unroll
        for (int i = 0; i < 3; ++i) {
            int col = i*16 + l15;
            if (col < N_CLSC) {
                float bias = bb2[col];
                #pragma unroll
                for (int r = 0; r < 4; ++r)
                    t2[(wv*16 + quad*4 + r)*72 + col] = (bf16)__expf(acc[i][r] + bias);
            }
        }
    }
    __syncthreads();
    // stream eow2 (src-order)
    #pragma unroll
    for (int i = 0; i < 2; ++i) {
        int idx = i*256 + tid;
        if (idx < 320) {
            int row = idx / 5, c8 = idx % 5;
            bf16x8 v = *(const bf16x8*)&t2[row*72 + c8*8];
            *(bf16x8*)&eow2[(size_t)(p0 + row)*N_CLSC + c8*8] = v;
        }
    }
    // seg-sum s2 (6 row-groups x 40 cols = 240 threads)
    if (tid < 240) {
        int c = tid % 40, g = tid / 40;
        int rA = g*11, rB = (rA + 11 < 64) ? rA + 11 : 64;
        float acc = 0.f;
        for (int r = rA; r < rB; ++r) {
            acc += (float)t2[r*72 + c];
            if (r == rB-1 || sv[r+1] != sv[r]) {
                atomicAdd(&s2[(size_t)sv[r]*N_CLSC + c], acc);
                acc = 0.f;
            }
        }
    }
}

// ------------- per-dst-node gather aggregation, fused ELU -------------
__global__ __launch_bounds__(256) void k_agg1(
    const bf16* __restrict__ eow1, const bf16* __restrict__ g1,
    const int* __restrict__ basev, const int* __restrict__ spd,
    const int* __restrict__ svd, float* __restrict__ out1) {
    int v = blockIdx.x, c = threadIdx.x;
    int b = basev[N_NODESC + v] - N_EDGESC;
    int e = (v < N_NODESC-1) ? basev[N_NODESC + v + 1] - N_EDGESC : N_EDGESC;
    float acc = 0.f;
    #pragma unroll 2
    for (int j = b; j < e; ++j) {
        int sp = spd[j], s = svd[j];
        acc += (float)eow1[(size_t)sp*HIDC + c] * (float)g1[(size_t)s*HIDC + c];
    }
    out1[(size_t)v*HIDC + c] = (acc > 0.f) ? acc : expm1f(acc);  // fused ELU
}

// ------------- layer-2 aggregation + fused log_softmax -------------
__global__ __launch_bounds__(64) void k_agg2(
    const bf16* __restrict__ eow2, const bf16* __restrict__ g2,
    const int* __restrict__ basev, const int* __restrict__ spd,
    const int* __restrict__ svd, float* __restrict__ out) {
    int v = blockIdx.x, c = threadIdx.x;
    int b = basev[N_NODESC + v] - N_EDGESC;
    int e = (v < N_NODESC-1) ? basev[N_NODESC + v + 1] - N_EDGESC : N_EDGESC;
    bool act = (c < N_CLSC);
    float acc = 0.f;
    #pragma unroll 2
    for (int j = b; j < e; ++j) {
        int sp = spd[j], s = svd[j];
        if (act) acc += (float)eow2[(size_t)sp*N_CLSC + c] * (float)g2[(size_t)s*N_CLSC + c];
    }
    float m = act ? acc : -INFINITY;
    #pragma unroll
    for (int off = 32; off > 0; off >>= 1) m = fmaxf(m, __shfl_xor(m, off));
    float ex = act ? __expf(acc - m) : 0.f;
    #pragma unroll
    for (int off = 32; off > 0; off >>= 1) ex += __shfl_xor(ex, off);
    if (act) out[(size_t)v*N_CLSC + c] = acc - m - logf(ex);
}

// ------------- small elementwise / dense kernels -------------
__global__ void k_div_bf4(bf16* __restrict__ h, const float* __restrict__ s, int n4) {
    int i = blockIdx.x*256 + threadIdx.x;
    if (i < n4) {
        bf16x4 hv = *(bf16x4*)&h[i*4];
        f32x4 sv = *(const f32x4*)&s[i*4];
        #pragma unroll
        for (int k = 0; k < 4; ++k) hv[k] = (bf16)((float)hv[k] / sv[k]);
        *(bf16x4*)&h[i*4] = hv;   // deg-0 rows: inf/nan, never gathered
    }
}
__global__ void k_h2(const float* __restrict__ out1, const float* __restrict__ W2,
                     const float* __restrict__ b2, bf16* __restrict__ h2) {
    int i = blockIdx.x*256 + threadIdx.x;
    if (i >= N_NODESC*N_CLSC) return;
    int v = i / N_CLSC, c = i - v*N_CLSC;
    float acc = b2[c];
    const float* row = &out1[(size_t)v*HIDC];
    #pragma unroll 4
    for (int k = 0; k < HIDC; ++k) acc += row[k] * W2[k*N_CLSC + c];
    h2[i] = (bf16)acc;
}

extern "C" void kernel_launch(void* const* d_in, const int* in_sizes, int n_in,
                              void* d_out, int out_size, void* d_ws, size_t ws_size,
                              hipStream_t stream) {
    const float* x    = (const float*)d_in[0];
    const int*   ei   = (const int*)d_in[1];
    const float* wmul = (const float*)d_in[2];
    const float* W1   = (const float*)d_in[3];
    const float* b1   = (const float*)d_in[4];
    const float* m1w0 = (const float*)d_in[5];
    const float* m1a  = (const float*)d_in[6];
    const float* m1w1 = (const float*)d_in[7];
    const float* m1b1 = (const float*)d_in[8];
    const float* W2   = (const float*)d_in[9];
    const float* b2   = (const float*)d_in[10];
    const float* m2w0 = (const float*)d_in[11];
    const float* m2a  = (const float*)d_in[12];
    const float* m2w1 = (const float*)d_in[13];
    const float* m2b1 = (const float*)d_in[14];
    float* out = (float*)d_out;

    char* ws = (char*)d_ws;
    size_t off = 0;
    auto alloc = [&](size_t bytes) -> void* {
        off = (off + 255) & ~(size_t)255;
        void* p = ws + off;
        off += bytes;
        return p;
    };
    // footprint ~574 MB (identical to R3's verified-fitting layout)
    bf16*  h1g1  = (bf16*) alloc((size_t)N_NODESC*HIDC*2);    // h1, then g1 in place
    float* s1o1  = (float*)alloc((size_t)N_NODESC*HIDC*4);    // s1 (atomics), then out1
    bf16*  h2g2  = (bf16*) alloc((size_t)N_NODESC*N_CLSC*2);  // h2, then g2
    float* s2    = (float*)alloc((size_t)N_NODESC*N_CLSC*4);
    bf16*  W1t   = (bf16*) alloc(256*512*2);
    bf16*  w0t   = (bf16*) alloc(256*64*2);
    bf16*  w1tm  = (bf16*) alloc(256*256*2);
    bf16*  w20t  = (bf16*) alloc(48*64*2);
    bf16*  w21t  = (bf16*) alloc(48*64*2);
    int*   hist  = (int*)  alloc(HN*4);
    int*   basev = (int*)  alloc(HN*4);
    int*   cursor= (int*)  alloc(HN*4);
    int*   part  = (int*)  alloc(256*4);
    int*   partx = (int*)  alloc(256*4);
    int*   perm_src = (int*)alloc((size_t)N_EDGESC*4);
    int*   spd      = (int*)alloc((size_t)N_EDGESC*4);
    int*   svd      = (int*)alloc((size_t)N_EDGESC*4);
    bf16*  eow1  = (bf16*) alloc((size_t)N_EDGESC*HIDC*2);    // u1, then exp in place
    bf16*  eow2  = (bf16*) alloc((size_t)N_EDGESC*N_CLSC*2);

    // --- CSR build (both directions) ---
    hipMemsetAsync(hist, 0, HN*4, stream);
    hipMemsetAsync(s1o1, 0, (size_t)N_NODESC*HIDC*4, stream);
    hipMemsetAsync(s2,   0, (size_t)N_NODESC*N_CLSC*4, stream);
    k_hist<<<(N_EDGESC+255)/256, 256, 0, stream>>>(ei, hist);
    k_scan_part<<<NB_SCAN, 512, 0, stream>>>(hist, part);
    k_scan_mid<<<1, 256, 0, stream>>>(part, partx);
    k_scan_apply<<<NB_SCAN, 512, 0, stream>>>(hist, partx, basev);
    k_copy<<<(HN+255)/256, 256, 0, stream>>>(cursor, basev, HN);
    k_scatter<<<(N_EDGESC+255)/256, 256, 0, stream>>>(ei, cursor, perm_src, spd, svd);

    // --- weight prep ---
    k_tconv<<<(512*256+255)/256, 256, 0, stream>>>(W1,   W1t, 512, 256, 512, 256);
    k_tconv<<<(256*64+255)/256,  256, 0, stream>>>(m1w0, w0t,  50, 256,  64, 256);
    k_tconv<<<(256*256+255)/256, 256, 0, stream>>>(m1w1, w1tm, 256, 256, 256, 256);
    k_tconv<<<(48*64+255)/256,   256, 0, stream>>>(m2w0, w20t,  50,  40,  64,  48);
    k_tconv<<<(48*64+255)/256,   256, 0, stream>>>(m2w1, w21t,  40,  40,  64,  48);

    // --- layer 1 ---
    k_h1<<<(N_NODESC+63)/64, 256, 0, stream>>>(x, W1t, b1, h1g1);
    k_mlp1a<<<N_EDGESC/64, 256, 0, stream>>>(wmul, perm_src, w0t, m1a, eow1);
    k_mlp1b<<<N_EDGESC/64, 256, 0, stream>>>(perm_src, ei, w1tm, m1b1, eow1, s1o1);
    k_mlp2<<<N_EDGESC/64, 256, 0, stream>>>(wmul, perm_src, ei, w20t, m2a, w21t, m2b1,
                                            eow2, s2);
    k_div_bf4<<<(N_NODESC*HIDC/4+255)/256, 256, 0, stream>>>(h1g1, s1o1, N_NODESC*HIDC/4); // g1
    k_agg1<<<N_NODESC, 256, 0, stream>>>(eow1, h1g1, basev, spd, svd, s1o1);               // out1 (+ELU)

    // --- layer 2 ---
    k_h2<<<(N_NODESC*N_CLSC+255)/256, 256, 0, stream>>>(s1o1, W2, b2, h2g2);
    k_div_bf4<<<(N_NODESC*N_CLSC/4+255)/256, 256, 0, stream>>>(h2g2, s2, N_NODESC*N_CLSC/4); // g2
    k_agg2<<<N_NODESC, 64, 0, stream>>>(eow2, h2g2, basev, spd, svd, out);                   // + log_softmax
}

// Round 5
// 1501.217 us; speedup vs baseline: 1.1624x; 1.1624x over previous
//
// CurvGN 2-layer GNN, MI355X gfx950. Round 5: re-fused MLP1 with register
// double-buffered K-loop. R4 post-mortem: mlp1b 440us at VGPR=76 -> compiler
// couldn't pipeline the 32 L2 B-frag loads; split also added 820 MB u1 round
// trip. R5: one fused MLP1 kernel (gather wm -> GEMM1 -> t1 LDS -> GEMM2 with
// af[2]/bf[2] double-buffer -> exp -> stream + segsum); MLP2 at M=128 with
// barrier-free stage1->stage2 (per-wave row ownership). Footprint 573.7 MB
// (proven: ws_size in [574,658) from R1 failure).
#include <hip/hip_runtime.h>
#include <hip/hip_bf16.h>
#include <math.h>

#define N_NODESC 50000
#define N_EDGESC 800000
#define F_INC 512
#define HIDC 256
#define N_CLSC 40
#define W_DIMC 50
#define HN (2*N_NODESC)
#define NB_SCAN 196   // ceil(100000/512)

typedef __bf16 bf16;
typedef __bf16 bf16x8 __attribute__((ext_vector_type(8)));
typedef __bf16 bf16x4 __attribute__((ext_vector_type(4)));
typedef __bf16 bf16x2 __attribute__((ext_vector_type(2)));
typedef float  f32x4  __attribute__((ext_vector_type(4)));
typedef float  f32x2  __attribute__((ext_vector_type(2)));

// ---------------- CSR build ----------------
__global__ void k_hist(const int* __restrict__ ei, int* __restrict__ hist) {
    int e = blockIdx.x*256 + threadIdx.x;
    if (e < N_EDGESC) {
        atomicAdd(&hist[ei[e]], 1);
        atomicAdd(&hist[N_NODESC + ei[N_EDGESC + e]], 1);
    }
}
__global__ void k_copy(int* d, const int* s, int n) {
    int i = blockIdx.x*256 + threadIdx.x;
    if (i < n) d[i] = s[i];
}
__global__ void k_scan_part(const int* __restrict__ hist, int* __restrict__ part) {
    __shared__ int lds[512];
    int t = threadIdx.x;
    int i = blockIdx.x*512 + t;
    lds[t] = (i < HN) ? hist[i] : 0;
    __syncthreads();
    for (int off = 256; off > 0; off >>= 1) {
        if (t < off) lds[t] += lds[t+off];
        __syncthreads();
    }
    if (t == 0) part[blockIdx.x] = lds[0];
}
__global__ void k_scan_mid(const int* __restrict__ part, int* __restrict__ partx) {
    __shared__ int lds[256];
    int t = threadIdx.x;
    int v = (t < NB_SCAN) ? part[t] : 0;
    lds[t] = v;
    __syncthreads();
    for (int off = 1; off < 256; off <<= 1) {
        int add = (t >= off) ? lds[t-off] : 0;
        __syncthreads();
        lds[t] += add;
        __syncthreads();
    }
    partx[t] = lds[t] - v;  // exclusive
}
__global__ void k_scan_apply(const int* __restrict__ hist, const int* __restrict__ partx,
                             int* __restrict__ basev) {
    __shared__ int lds[512];
    int t = threadIdx.x;
    int i = blockIdx.x*512 + t;
    int v = (i < HN) ? hist[i] : 0;
    lds[t] = v;
    __syncthreads();
    for (int off = 1; off < 512; off <<= 1) {
        int add = (t >= off) ? lds[t-off] : 0;
        __syncthreads();
        lds[t] += add;
        __syncthreads();
    }
    if (i < HN) basev[i] = lds[t] - v + partx[blockIdx.x];
}
// perm_src[p]=e (src-order); spd[q]=p, svd[q]=src (dst-order)
__global__ void k_scatter(const int* __restrict__ ei, int* __restrict__ cursor,
                          int* __restrict__ perm_src,
                          int* __restrict__ spd, int* __restrict__ svd) {
    int e = blockIdx.x*256 + threadIdx.x;
    if (e >= N_EDGESC) return;
    int s = ei[e];
    int d = ei[N_EDGESC + e];
    int p = atomicAdd(&cursor[s], 1);
    perm_src[p] = e;
    int q = atomicAdd(&cursor[N_NODESC + d], 1) - N_EDGESC;
    spd[q] = p;
    svd[q] = s;
}

// ------------- weight transpose/convert: dst[n*Kp+k] = src[k*Ns+n] -------------
__global__ void k_tconv(const float* __restrict__ src, bf16* __restrict__ dst,
                        int Ks, int Ns, int Kp, int Np) {
    int idx = blockIdx.x*256 + threadIdx.x;
    if (idx >= Kp*Np) return;
    int n = idx / Kp, k = idx - n*Kp;
    float v = (k < Ks && n < Ns) ? src[k*Ns + n] : 0.f;
    dst[idx] = (bf16)v;
}

// ------------- h1 = x @ W1 + b1  (bf16 MFMA, bf16 out) -------------
__global__ __launch_bounds__(256) void k_h1(const float* __restrict__ x,
                                            const bf16* __restrict__ W1t,
                                            const float* __restrict__ b1,
                                            bf16* __restrict__ h1) {
    __shared__ __align__(16) bf16 a_lds[64*40];
    int tid = threadIdx.x;
    int lane = tid & 63, wv = tid >> 6;
    int l15 = lane & 15, quad = lane >> 4;
    int r0 = blockIdx.x * 64;
    f32x4 acc[4][4] = {};
    for (int ks = 0; ks < 16; ++ks) {
        #pragma unroll
        for (int i = 0; i < 2; ++i) {
            int idx = tid + i*256;          // 512 float4 = 64 rows x 32 k
            int rl = idx >> 3, c4 = idx & 7;
            int rg = r0 + rl;
            f32x4 v = {};
            if (rg < N_NODESC) v = *(const f32x4*)&x[(size_t)rg*F_INC + ks*32 + c4*4];
            bf16x4 b; b[0]=(bf16)v[0]; b[1]=(bf16)v[1]; b[2]=(bf16)v[2]; b[3]=(bf16)v[3];
            *(bf16x4*)&a_lds[rl*40 + c4*4] = b;
        }
        __syncthreads();
        bf16x8 af[4], bfr[4];
        #pragma unroll
        for (int mt = 0; mt < 4; ++mt)
            af[mt] = *(const bf16x8*)&a_lds[(mt*16 + l15)*40 + quad*8];
        #pragma unroll
        for (int nt = 0; nt < 4; ++nt) {
            int n = wv*64 + nt*16 + l15;
            bfr[nt] = *(const bf16x8*)&W1t[n*F_INC + ks*32 + quad*8];
        }
        #pragma unroll
        for (int mt = 0; mt < 4; ++mt)
            #pragma unroll
            for (int nt = 0; nt < 4; ++nt)
                acc[mt][nt] = __builtin_amdgcn_mfma_f32_16x16x32_bf16(af[mt], bfr[nt], acc[mt][nt], 0, 0, 0);
        __syncthreads();
    }
    #pragma unroll
    for (int nt = 0; nt < 4; ++nt) {
        int col = wv*64 + nt*16 + l15;
        float bias = b1[col];
        #pragma unroll
        for (int mt = 0; mt < 4; ++mt)
            #pragma unroll
            for (int r = 0; r < 4; ++r) {
                int row = r0 + mt*16 + quad*4 + r;
                if (row < N_NODESC) h1[(size_t)row*HIDC + col] = (bf16)(acc[mt][nt][r] + bias);
            }
    }
}

// ------------- fused MLP1 (both stages) + eow1 stream + s1 segsum -------------
__global__ __launch_bounds__(256) void k_mlp1(
    const float* __restrict__ w_mul, const int* __restrict__ perm_src,
    const int* __restrict__ ei,
    const bf16* __restrict__ w0t, const float* __restrict__ a1,
    const bf16* __restrict__ w1t, const float* __restrict__ bb1,
    bf16* __restrict__ eow1, float* __restrict__ s1) {
    __shared__ __align__(16) bf16 wm[64*72];    // A tile, K padded 50->64
    __shared__ __align__(16) bf16 t1[64*264];   // hidden / exp tile
    __shared__ int e_lds[64], sv[64];
    int tid = threadIdx.x;
    int lane = tid & 63, wv = tid >> 6;
    int l15 = lane & 15, quad = lane >> 4;
    int p0 = blockIdx.x * 64;

    if (tid < 64) {
        int e = perm_src[p0 + tid];
        e_lds[tid] = e;
        sv[tid] = ei[e];
    }
    __syncthreads();
    // gather w_mul rows as f32x2 -> bf16x2 (64 rows x 25 pairs)
    #pragma unroll
    for (int i = 0; i < 7; ++i) {
        int idx = i*256 + tid;
        if (idx < 1600) {
            int row = idx / 25;
            int k = 2*(idx - row*25);
            f32x2 v = *(const f32x2*)&w_mul[(size_t)e_lds[row]*W_DIMC + k];
            bf16x2 b; b[0] = (bf16)v[0]; b[1] = (bf16)v[1];
            *(bf16x2*)&wm[row*72 + k] = b;
        }
    }
    #pragma unroll
    for (int i = 0; i < 2; ++i) {   // zero pad cols 50..63
        int idx = i*256 + tid;
        if (idx < 448) {
            int row = idx / 7, c = 50 + 2*(idx - row*7);
            bf16x2 z; z[0] = (bf16)0.f; z[1] = (bf16)0.f;
            *(bf16x2*)&wm[row*72 + c] = z;
        }
    }
    __syncthreads();

    // ---- stage 1: z = wm @ w0t, prelu -> t1  (K=64: load-all then MFMA)
    {
        f32x4 acc[4][4] = {};
        bf16x8 af[2][4], bfr[2][4];
        #pragma unroll
        for (int ks = 0; ks < 2; ++ks) {
            #pragma unroll
            for (int mt = 0; mt < 4; ++mt)
                af[ks][mt] = *(const bf16x8*)&wm[(mt*16 + l15)*72 + ks*32 + quad*8];
            #pragma unroll
            for (int i = 0; i < 4; ++i)
                bfr[ks][i] = *(const bf16x8*)&w0t[(wv*64 + i*16 + l15)*64 + ks*32 + quad*8];
        }
        #pragma unroll
        for (int ks = 0; ks < 2; ++ks)
            #pragma unroll
            for (int mt = 0; mt < 4; ++mt)
                #pragma unroll
                for (int i = 0; i < 4; ++i)
                    acc[mt][i] = __builtin_amdgcn_mfma_f32_16x16x32_bf16(af[ks][mt], bfr[ks][i], acc[mt][i], 0, 0, 0);
        #pragma unroll
        for (int i = 0; i < 4; ++i) {
            int col = wv*64 + i*16 + l15;
            float al = a1[col];
            #pragma unroll
            for (int mt = 0; mt < 4; ++mt)
                #pragma unroll
                for (int r = 0; r < 4; ++r) {
                    float v = acc[mt][i][r];
                    v = (v >= 0.f) ? v : al*v;
                    t1[(mt*16 + quad*4 + r)*264 + col] = (bf16)v;
                }
        }
    }
    __syncthreads();

    // ---- stage 2: y = t1 @ w1t (K=256), register double-buffered pipeline
    {
        f32x4 acc[4][4] = {};
        bf16x8 af[2][4], bfr[2][4];
        #pragma unroll
        for (int mt = 0; mt < 4; ++mt)
            af[0][mt] = *(const bf16x8*)&t1[(mt*16 + l15)*264 + quad*8];
        #pragma unroll
        for (int i = 0; i < 4; ++i)
            bfr[0][i] = *(const bf16x8*)&w1t[(wv*64 + i*16 + l15)*HIDC + quad*8];
        #pragma unroll
        for (int ks = 0; ks < 8; ++ks) {
            int cur = ks & 1, nxt = cur ^ 1;
            if (ks < 7) {   // prefetch ks+1 before consuming ks
                #pragma unroll
                for (int mt = 0; mt < 4; ++mt)
                    af[nxt][mt] = *(const bf16x8*)&t1[(mt*16 + l15)*264 + (ks+1)*32 + quad*8];
                #pragma unroll
                for (int i = 0; i < 4; ++i)
                    bfr[nxt][i] = *(const bf16x8*)&w1t[(wv*64 + i*16 + l15)*HIDC + (ks+1)*32 + quad*8];
            }
            #pragma unroll
            for (int mt = 0; mt < 4; ++mt)
                #pragma unroll
                for (int i = 0; i < 4; ++i)
                    acc[mt][i] = __builtin_amdgcn_mfma_f32_16x16x32_bf16(af[cur][mt], bfr[cur][i], acc[mt][i], 0, 0, 0);
        }
        __syncthreads();   // all t1 reads complete before overwrite
        #pragma unroll
        for (int i = 0; i < 4; ++i) {
            int col = wv*64 + i*16 + l15;
            float bias = bb1[col];
            #pragma unroll
            for (int mt = 0; mt < 4; ++mt)
                #pragma unroll
                for (int r = 0; r < 4; ++r)
                    t1[(mt*16 + quad*4 + r)*264 + col] = (bf16)__expf(acc[mt][i][r] + bias);
        }
    }
    __syncthreads();

    // ---- stream eow1 (src-order, coalesced bf16x8)
    #pragma unroll
    for (int i = 0; i < 8; ++i) {
        int idx = i*256 + tid;
        int row = idx >> 5, j = idx & 31;
        *(bf16x8*)&eow1[(size_t)(p0 + row)*HIDC + j*8] = *(const bf16x8*)&t1[row*264 + j*8];
    }
    // ---- seg-sum s1 (fixed-trip, wave-uniform flush)
    {
        int c = tid;
        float acc2 = 0.f;
        #pragma unroll
        for (int r = 0; r < 64; ++r) {
            acc2 += (float)t1[r*264 + c];
            if (r == 63 || sv[r+1] != sv[r]) {
                atomicAdd(&s1[(size_t)sv[r]*HIDC + c], acc2);
                acc2 = 0.f;
            }
        }
    }
}

// ------------- MLP2 (both stages), M=128, barrier-light -------------
__global__ __launch_bounds__(256) void k_mlp2(
    const float* __restrict__ w_mul, const int* __restrict__ perm_src,
    const int* __restrict__ ei,
    const bf16* __restrict__ w20t, const float* __restrict__ a2,
    const bf16* __restrict__ w21t, const float* __restrict__ bb2,
    bf16* __restrict__ eow2, float* __restrict__ s2) {
    __shared__ __align__(16) bf16 wm[128*72];
    __shared__ __align__(16) bf16 t2[128*72];
    __shared__ int e_lds[128], sv[128];
    int tid = threadIdx.x;
    int lane = tid & 63, wv = tid >> 6;
    int l15 = lane & 15, quad = lane >> 4;
    int p0 = blockIdx.x * 128;       // E = 6250*128 exactly

    if (tid < 128) {
        int e = perm_src[p0 + tid];
        e_lds[tid] = e;
        sv[tid] = ei[e];
    }
    __syncthreads();
    // gather wm (128 rows x 25 f32x2)
    #pragma unroll
    for (int i = 0; i < 13; ++i) {
        int idx = i*256 + tid;
        if (idx < 3200) {
            int row = idx / 25;
            int k = 2*(idx - row*25);
            f32x2 v = *(const f32x2*)&w_mul[(size_t)e_lds[row]*W_DIMC + k];
            bf16x2 b; b[0] = (bf16)v[0]; b[1] = (bf16)v[1];
            *(bf16x2*)&wm[row*72 + k] = b;
        }
    }
    #pragma unroll
    for (int i = 0; i < 4; ++i) {   // wm pad cols 50..63 (128 rows x 7 bf16x2)
        int idx = i*256 + tid;
        if (idx < 896) {
            int row = idx / 7, c = 50 + 2*(idx - row*7);
            bf16x2 z; z[0] = (bf16)0.f; z[1] = (bf16)0.f;
            *(bf16x2*)&wm[row*72 + c] = z;
        }
    }
    #pragma unroll
    for (int i = 0; i < 4; ++i) {   // t2 pad cols 48..63 (128 rows x 8 bf16x2)
        int idx = i*256 + tid;
        int row = idx >> 3, c = 48 + 2*(idx & 7);
        bf16x2 z; z[0] = (bf16)0.f; z[1] = (bf16)0.f;
        *(bf16x2*)&t2[row*72 + c] = z;
    }
    __syncthreads();

    // stage 1: wave wv owns rows wv*32..+31; N=48; K=64
    {
        f32x4 acc[2][3] = {};
        #pragma unroll
        for (int ks = 0; ks < 2; ++ks) {
            bf16x8 af[2], bfr[3];
            #pragma unroll
            for (int mt = 0; mt < 2; ++mt)
                af[mt] = *(const bf16x8*)&wm[(wv*32 + mt*16 + l15)*72 + ks*32 + quad*8];
            #pragma unroll
            for (int i = 0; i < 3; ++i)
                bfr[i] = *(const bf16x8*)&w20t[(i*16 + l15)*64 + ks*32 + quad*8];
            #pragma unroll
            for (int mt = 0; mt < 2; ++mt)
                #pragma unroll
                for (int i = 0; i < 3; ++i)
                    acc[mt][i] = __builtin_amdgcn_mfma_f32_16x16x32_bf16(af[mt], bfr[i], acc[mt][i], 0, 0, 0);
        }
        #pragma unroll
        for (int i = 0; i < 3; ++i) {
            int col = i*16 + l15;
            float al = (col < N_CLSC) ? a2[col] : 0.f;
            #pragma unroll
            for (int mt = 0; mt < 2; ++mt)
                #pragma unroll
                for (int r = 0; r < 4; ++r) {
                    float v = acc[mt][i][r];
                    v = (v >= 0.f) ? v : al*v;
                    t2[(wv*32 + mt*16 + quad*4 + r)*72 + col] = (bf16)v;
                }
        }
    }
    // NO barrier: stage 2 reads only this wave's own 32 rows (lgkmcnt dep only)

    // stage 2: t2(own rows) @ w21t -> exp -> overwrite own rows cols<40
    {
        f32x4 acc[2][3] = {};
        #pragma unroll
        for (int ks = 0; ks < 2; ++ks) {
            bf16x8 af[2], bfr[3];
            #pragma unroll
            for (int mt = 0; mt < 2; ++mt)
                af[mt] = *(const bf16x8*)&t2[(wv*32 + mt*16 + l15)*72 + ks*32 + quad*8];
            #pragma unroll
            for (int i = 0; i < 3; ++i)
                bfr[i] = *(const bf16x8*)&w21t[(i*16 + l15)*64 + ks*32 + quad*8];
            #pragma unroll
            for (int mt = 0; mt < 2; ++mt)
                #pragma unroll
                for (int i = 0; i < 3; ++i)
                    acc[mt][i] = __builtin_amdgcn_mfma_f32_16x16x32_bf16(af[mt], bfr[i], acc[mt][i], 0, 0, 0);
        }
        #pragma unroll
        for (int i = 0; i < 3; ++i) {
            int col = i*16 + l15;
            if (col < N_CLSC) {
                float bias = bb2[col];
                #pragma unroll
                for (int mt = 0; mt < 2; ++mt)
                    #pragma unroll
                    for (int r = 0; r < 4; ++r)
                        t2[(wv*32 + mt*16 + quad*4 + r)*72 + col] = (bf16)__expf(acc[mt][i][r] + bias);
            }
        }
    }
    __syncthreads();   // cross-wave reads below

    // stream eow2 (src-order; 128 rows x 5 bf16x8 = 640 chunks)
    #pragma unroll
    for (int i = 0; i < 3; ++i) {
        int idx = i*256 + tid;
        if (idx < 640) {
            int row = idx / 5, c8 = idx % 5;
            bf16x8 v = *(const bf16x8*)&t2[row*72 + c8*8];
            *(bf16x8*)&eow2[(size_t)(p0 + row)*N_CLSC + c8*8] = v;
        }
    }
    // seg-sum s2 (6 row-groups x 40 cols = 240 threads; 22 rows/group)
    if (tid < 240) {
        int c = tid % 40, g = tid / 40;
        int rA = g*22, rB = (rA + 22 < 128) ? rA + 22 : 128;
        float acc = 0.f;
        for (int r = rA; r < rB; ++r) {
            acc += (float)t2[r*72 + c];
            if (r == rB-1 || sv[r+1] != sv[r]) {
                atomicAdd(&s2[(size_t)sv[r]*N_CLSC + c], acc);
                acc = 0.f;
            }
        }
    }
}

// ------------- per-dst-node gather aggregation, fused ELU -------------
__global__ __launch_bounds__(256) void k_agg1(
    const bf16* __restrict__ eow1, const bf16* __restrict__ g1,
    const int* __restrict__ basev, const int* __restrict__ spd,
    const int* __restrict__ svd, float* __restrict__ out1) {
    int v = blockIdx.x, c = threadIdx.x;
    int b = basev[N_NODESC + v] - N_EDGESC;
    int e = (v < N_NODESC-1) ? basev[N_NODESC + v + 1] - N_EDGESC : N_EDGESC;
    float acc = 0.f;
    #pragma unroll 2
    for (int j = b; j < e; ++j) {
        int sp = spd[j], s = svd[j];
        acc += (float)eow1[(size_t)sp*HIDC + c] * (float)g1[(size_t)s*HIDC + c];
    }
    out1[(size_t)v*HIDC + c] = (acc > 0.f) ? acc : expm1f(acc);  // fused ELU
}

// ------------- layer-2 aggregation + fused log_softmax -------------
__global__ __launch_bounds__(64) void k_agg2(
    const bf16* __restrict__ eow2, const bf16* __restrict__ g2,
    const int* __restrict__ basev, const int* __restrict__ spd,
    const int* __restrict__ svd, float* __restrict__ out) {
    int v = blockIdx.x, c = threadIdx.x;
    int b = basev[N_NODESC + v] - N_EDGESC;
    int e = (v < N_NODESC-1) ? basev[N_NODESC + v + 1] - N_EDGESC : N_EDGESC;
    bool act = (c < N_CLSC);
    float acc = 0.f;
    #pragma unroll 2
    for (int j = b; j < e; ++j) {
        int sp = spd[j], s = svd[j];
        if (act) acc += (float)eow2[(size_t)sp*N_CLSC + c] * (float)g2[(size_t)s*N_CLSC + c];
    }
    float m = act ? acc : -INFINITY;
    #pragma unroll
    for (int off = 32; off > 0; off >>= 1) m = fmaxf(m, __shfl_xor(m, off));
    float ex = act ? __expf(acc - m) : 0.f;
    #pragma unroll
    for (int off = 32; off > 0; off >>= 1) ex += __shfl_xor(ex, off);
    if (act) out[(size_t)v*N_CLSC + c] = acc - m - logf(ex);
}

// ------------- small elementwise / dense kernels -------------
__global__ void k_div_bf4(bf16* __restrict__ h, const float* __restrict__ s, int n4) {
    int i = blockIdx.x*256 + threadIdx.x;
    if (i < n4) {
        bf16x4 hv = *(bf16x4*)&h[i*4];
        f32x4 sv = *(const f32x4*)&s[i*4];
        #pragma unroll
        for (int k = 0; k < 4; ++k) hv[k] = (bf16)((float)hv[k] / sv[k]);
        *(bf16x4*)&h[i*4] = hv;   // deg-0 rows: inf/nan, never gathered
    }
}
__global__ void k_h2(const float* __restrict__ out1, const float* __restrict__ W2,
                     const float* __restrict__ b2, bf16* __restrict__ h2) {
    int i = blockIdx.x*256 + threadIdx.x;
    if (i >= N_NODESC*N_CLSC) return;
    int v = i / N_CLSC, c = i - v*N_CLSC;
    float acc = b2[c];
    const float* row = &out1[(size_t)v*HIDC];
    #pragma unroll 4
    for (int k = 0; k < HIDC; ++k) acc += row[k] * W2[k*N_CLSC + c];
    h2[i] = (bf16)acc;
}

extern "C" void kernel_launch(void* const* d_in, const int* in_sizes, int n_in,
                              void* d_out, int out_size, void* d_ws, size_t ws_size,
                              hipStream_t stream) {
    const float* x    = (const float*)d_in[0];
    const int*   ei   = (const int*)d_in[1];
    const float* wmul = (const float*)d_in[2];
    const float* W1   = (const float*)d_in[3];
    const float* b1   = (const float*)d_in[4];
    const float* m1w0 = (const float*)d_in[5];
    const float* m1a  = (const float*)d_in[6];
    const float* m1w1 = (const float*)d_in[7];
    const float* m1b1 = (const float*)d_in[8];
    const float* W2   = (const float*)d_in[9];
    const float* b2   = (const float*)d_in[10];
    const float* m2w0 = (const float*)d_in[11];
    const float* m2a  = (const float*)d_in[12];
    const float* m2w1 = (const float*)d_in[13];
    const float* m2b1 = (const float*)d_in[14];
    float* out = (float*)d_out;

    char* ws = (char*)d_ws;
    size_t off = 0;
    auto alloc = [&](size_t bytes) -> void* {
        off = (off + 255) & ~(size_t)255;
        void* p = ws + off;
        off += bytes;
        return p;
    };
    // footprint ~573.7 MB (identical to R3/R4 proven layout)
    bf16*  h1g1  = (bf16*) alloc((size_t)N_NODESC*HIDC*2);    // h1, then g1 in place
    float* s1o1  = (float*)alloc((size_t)N_NODESC*HIDC*4);    // s1 (atomics), then out1
    bf16*  h2g2  = (bf16*) alloc((size_t)N_NODESC*N_CLSC*2);  // h2, then g2
    float* s2    = (float*)alloc((size_t)N_NODESC*N_CLSC*4);
    bf16*  W1t   = (bf16*) alloc(256*512*2);
    bf16*  w0t   = (bf16*) alloc(256*64*2);
    bf16*  w1tm  = (bf16*) alloc(256*256*2);
    bf16*  w20t  = (bf16*) alloc(48*64*2);
    bf16*  w21t  = (bf16*) alloc(48*64*2);
    int*   hist  = (int*)  alloc(HN*4);
    int*   basev = (int*)  alloc(HN*4);
    int*   cursor= (int*)  alloc(HN*4);
    int*   part  = (int*)  alloc(256*4);
    int*   partx = (int*)  alloc(256*4);
    int*   perm_src = (int*)alloc((size_t)N_EDGESC*4);
    int*   spd      = (int*)alloc((size_t)N_EDGESC*4);
    int*   svd      = (int*)alloc((size_t)N_EDGESC*4);
    bf16*  eow1  = (bf16*) alloc((size_t)N_EDGESC*HIDC*2);    // 410 MB, src-order
    bf16*  eow2  = (bf16*) alloc((size_t)N_EDGESC*N_CLSC*2);  //  64 MB, src-order

    // --- CSR build (both directions) ---
    hipMemsetAsync(hist, 0, HN*4, stream);
    hipMemsetAsync(s1o1, 0, (size_t)N_NODESC*HIDC*4, stream);
    hipMemsetAsync(s2,   0, (size_t)N_NODESC*N_CLSC*4, stream);
    k_hist<<<(N_EDGESC+255)/256, 256, 0, stream>>>(ei, hist);
    k_scan_part<<<NB_SCAN, 512, 0, stream>>>(hist, part);
    k_scan_mid<<<1, 256, 0, stream>>>(part, partx);
    k_scan_apply<<<NB_SCAN, 512, 0, stream>>>(hist, partx, basev);
    k_copy<<<(HN+255)/256, 256, 0, stream>>>(cursor, basev, HN);
    k_scatter<<<(N_EDGESC+255)/256, 256, 0, stream>>>(ei, cursor, perm_src, spd, svd);

    // --- weight prep ---
    k_tconv<<<(512*256+255)/256, 256, 0, stream>>>(W1,   W1t, 512, 256, 512, 256);
    k_tconv<<<(256*64+255)/256,  256, 0, stream>>>(m1w0, w0t,  50, 256,  64, 256);
    k_tconv<<<(256*256+255)/256, 256, 0, stream>>>(m1w1, w1tm, 256, 256, 256, 256);
    k_tconv<<<(48*64+255)/256,   256, 0, stream>>>(m2w0, w20t,  50,  40,  64,  48);
    k_tconv<<<(48*64+255)/256,   256, 0, stream>>>(m2w1, w21t,  40,  40,  64,  48);

    // --- layer 1 ---
    k_h1<<<(N_NODESC+63)/64, 256, 0, stream>>>(x, W1t, b1, h1g1);
    k_mlp1<<<N_EDGESC/64, 256, 0, stream>>>(wmul, perm_src, ei, w0t, m1a, w1tm, m1b1,
                                            eow1, s1o1);
    k_mlp2<<<N_EDGESC/128, 256, 0, stream>>>(wmul, perm_src, ei, w20t, m2a, w21t, m2b1,
                                             eow2, s2);
    k_div_bf4<<<(N_NODESC*HIDC/4+255)/256, 256, 0, stream>>>(h1g1, s1o1, N_NODESC*HIDC/4); // g1
    k_agg1<<<N_NODESC, 256, 0, stream>>>(eow1, h1g1, basev, spd, svd, s1o1);               // out1 (+ELU)

    // --- layer 2 ---
    k_h2<<<(N_NODESC*N_CLSC+255)/256, 256, 0, stream>>>(s1o1, W2, b2, h2g2);
    k_div_bf4<<<(N_NODESC*N_CLSC/4+255)/256, 256, 0, stream>>>(h2g2, s2, N_NODESC*N_CLSC/4); // g2
    k_agg2<<<N_NODESC, 64, 0, stream>>>(eow2, h2g2, basev, spd, svd, out);                   // + log_softmax
}